// Round 1
// baseline (7345.061 us; speedup 1.0000x reference)
//
#include <hip/hip_runtime.h>

// AFNO2D: y = irfft2_ortho( MLP( rfft2_ortho(x) ) ) + x
// B=8, H=128, W=128, C=768, NUM_BLOCKS=8, bs=96, HSF=1, lambda=0.01
// HARD_FRAC=1.0 -> all modes kept (h0=0,h1=128,w1k=65).

#define B_DIM 8
#define H_DIM 128
#define W_DIM 128
#define C_DIM 768
#define WF    65
#define NBLK  8
#define BS    96
#define LAMBDA 0.01f
#define TWO_PI_OVER_N 0.04908738521234052f   // 2*pi/128

// ---------------------------------------------------------------------------
// K1: rfft along W (direct DFT, 65 outputs from 128 reals), fold 1/128 (ortho fwd)
// grid: (B*H) * 12 c-tiles of 64 ; block 256
// ---------------------------------------------------------------------------
__global__ __launch_bounds__(256) void k1_rfft_w(const float* __restrict__ x,
                                                 float2* __restrict__ S) {
    const int blk   = blockIdx.x;
    const int ctile = blk % 12;
    const int bh    = blk / 12;          // b*128 + h
    const int c0    = ctile * 64;

    __shared__ float xs[W_DIM][64];
    __shared__ float cs[128], sn[128];

    const int tid = threadIdx.x;
    if (tid < 128) {
        float sv, cv;
        sincosf(TWO_PI_OVER_N * (float)tid, &sv, &cv);
        cs[tid] = cv; sn[tid] = sv;
    }
    const size_t xbase = (size_t)bh * (W_DIM * C_DIM) + c0;
    for (int idx = tid; idx < W_DIM * 64; idx += 256) {
        int w = idx >> 6, c = idx & 63;
        xs[w][c] = x[xbase + (size_t)w * C_DIM + c];
    }
    __syncthreads();

    const int c   = tid & 63;
    const int kw0 = tid >> 6;            // 0..3 (wave-uniform)
    for (int kw = kw0; kw <= 64; kw += 4) {
        float ar = 0.f, ai = 0.f;
        for (int w = 0; w < 128; ++w) {
            int t = (kw * w) & 127;
            float v = xs[w][c];
            ar = fmaf(v, cs[t], ar);
            ai = fmaf(-v, sn[t], ai);
        }
        S[((size_t)bh * WF + kw) * C_DIM + c0 + c] =
            make_float2(ar * 0.0078125f, ai * 0.0078125f);
    }
}

// ---------------------------------------------------------------------------
// K2/K4: complex DFT along H, in-place per (b,kw,ctile of 32) slab.
// INV=false: e^{-i}, no scale. INV=true: e^{+i}, scale 1/128 (ortho inv total).
// grid: B*WF*24 ; block 256
// ---------------------------------------------------------------------------
template <bool INV>
__global__ __launch_bounds__(256) void k_fft_h(float2* __restrict__ S) {
    const int blk   = blockIdx.x;
    const int ctile = blk % 24;
    const int rest  = blk / 24;
    const int kw    = rest % WF;
    const int b     = rest / WF;
    const int c0    = ctile * 32;

    __shared__ float2 zs[H_DIM][32];
    __shared__ float cs[128], sn[128];

    const int tid = threadIdx.x;
    if (tid < 128) {
        float sv, cv;
        sincosf(TWO_PI_OVER_N * (float)tid, &sv, &cv);
        cs[tid] = cv; sn[tid] = sv;
    }
    const size_t base = (((size_t)b * H_DIM) * WF + kw) * C_DIM + c0;
    const size_t hstр = (size_t)WF * C_DIM;
    for (int idx = tid; idx < H_DIM * 32; idx += 256) {
        int h = idx >> 5, c = idx & 31;
        zs[h][c] = S[base + (size_t)h * hstр + c];
    }
    __syncthreads();

    const int c   = tid & 31;
    const int kh0 = tid >> 5;            // 0..7
    for (int kh = kh0; kh < 128; kh += 8) {
        float ar = 0.f, ai = 0.f;
        for (int h = 0; h < 128; ++h) {
            int t = (kh * h) & 127;
            float2 z = zs[h][c];
            if (!INV) {                  // * (cos - i sin)
                ar = fmaf(z.x, cs[t], fmaf( z.y, sn[t], ar));
                ai = fmaf(z.y, cs[t], fmaf(-z.x, sn[t], ai));
            } else {                     // * (cos + i sin)
                ar = fmaf(z.x, cs[t], fmaf(-z.y, sn[t], ar));
                ai = fmaf(z.y, cs[t], fmaf( z.x, sn[t], ai));
            }
        }
        if (INV) { ar *= 0.0078125f; ai *= 0.0078125f; }
        S[base + (size_t)kh * hstр + c] = make_float2(ar, ai);
    }
}

// ---------------------------------------------------------------------------
// K3: per-mode block-diagonal complex 2-layer MLP, in-place on S.
// grid: (66560/16 position tiles, 8 blocks) ; block 192
// ---------------------------------------------------------------------------
__device__ __forceinline__ float softshrinkf(float v) {
    return v > LAMBDA ? v - LAMBDA : (v < -LAMBDA ? v + LAMBDA : 0.f);
}

__global__ __launch_bounds__(192) void k3_mlp(float2* __restrict__ S,
                                              const float* __restrict__ w1,
                                              const float* __restrict__ b1,
                                              const float* __restrict__ w2,
                                              const float* __restrict__ b2) {
    const int n     = blockIdx.y;
    const int pbase = blockIdx.x * 16;
    const int c0    = n * BS;

    __shared__ float2 xin[16][BS];
    __shared__ float2 o1s[16][BS];

    const int tid = threadIdx.x;
    for (int idx = tid; idx < 16 * BS; idx += 192) {
        int p = idx / BS, c = idx - p * BS;
        xin[p][c] = S[(size_t)(pbase + p) * C_DIM + c0 + c];
    }
    __syncthreads();

    const int o  = tid % BS;   // output index
    const int ph = tid / BS;   // 0/1: which half of the 16 positions

    float ar[8], ai[8];
    #pragma unroll
    for (int j = 0; j < 8; ++j) { ar[j] = 0.f; ai[j] = 0.f; }

    // layer 1: o1 = relu( x * (W1r + i W1i) + (b1r + i b1i) )
    const float* W1r = w1 + (size_t)n * BS * BS;
    const float* W1i = w1 + (size_t)(NBLK + n) * BS * BS;
    for (int i = 0; i < BS; ++i) {
        float wr = W1r[i * BS + o], wi = W1i[i * BS + o];
        #pragma unroll
        for (int j = 0; j < 8; ++j) {
            float2 z = xin[ph + 2 * j][i];
            ar[j] = fmaf(z.x, wr, fmaf(-z.y, wi, ar[j]));
            ai[j] = fmaf(z.y, wr, fmaf( z.x, wi, ai[j]));
        }
    }
    {
        float br = b1[n * BS + o], bi = b1[(NBLK + n) * BS + o];
        #pragma unroll
        for (int j = 0; j < 8; ++j) {
            o1s[ph + 2 * j][o] = make_float2(fmaxf(ar[j] + br, 0.f),
                                             fmaxf(ai[j] + bi, 0.f));
        }
    }
    __syncthreads();

    #pragma unroll
    for (int j = 0; j < 8; ++j) { ar[j] = 0.f; ai[j] = 0.f; }

    // layer 2: o2 = softshrink( o1 * (W2r + i W2i) + b2 )
    const float* W2r = w2 + (size_t)n * BS * BS;
    const float* W2i = w2 + (size_t)(NBLK + n) * BS * BS;
    for (int i = 0; i < BS; ++i) {       // i = hidden index, o = final output index
        float wr = W2r[i * BS + o], wi = W2i[i * BS + o];
        #pragma unroll
        for (int j = 0; j < 8; ++j) {
            float2 z = o1s[ph + 2 * j][i];
            ar[j] = fmaf(z.x, wr, fmaf(-z.y, wi, ar[j]));
            ai[j] = fmaf(z.y, wr, fmaf( z.x, wi, ai[j]));
        }
    }
    {
        float br = b2[n * BS + o], bi = b2[(NBLK + n) * BS + o];
        #pragma unroll
        for (int j = 0; j < 8; ++j) {
            S[(size_t)(pbase + ph + 2 * j) * C_DIM + c0 + o] =
                make_float2(softshrinkf(ar[j] + br), softshrinkf(ai[j] + bi));
        }
    }
}

// ---------------------------------------------------------------------------
// K5: C2R inverse rfft along W + bias add.
// y[w] = Z0.r + (-1)^w Z64.r + 2*sum_{k=1..63}(Zk.r cos - Zk.i sin) ; + x
// (pocketfft C2R convention: imag of DC/Nyquist ignored.)
// grid: (B*H) * 24 c-tiles of 32 ; block 256
// ---------------------------------------------------------------------------
__global__ __launch_bounds__(256) void k5_irfft_w(const float2* __restrict__ S,
                                                  const float* __restrict__ x,
                                                  float* __restrict__ out) {
    const int blk   = blockIdx.x;
    const int ctile = blk % 24;
    const int bh    = blk / 24;
    const int c0    = ctile * 32;

    __shared__ float2 zs[WF][32];
    __shared__ float cs[128], sn[128];

    const int tid = threadIdx.x;
    if (tid < 128) {
        float sv, cv;
        sincosf(TWO_PI_OVER_N * (float)tid, &sv, &cv);
        cs[tid] = cv; sn[tid] = sv;
    }
    const size_t sbase = (size_t)bh * WF * C_DIM + c0;
    for (int idx = tid; idx < WF * 32; idx += 256) {
        int k = idx >> 5, c = idx & 31;
        zs[k][c] = S[sbase + (size_t)k * C_DIM + c];
    }
    __syncthreads();

    const int c  = tid & 31;
    const int w0 = tid >> 5;             // 0..7
    const size_t obase = (size_t)bh * (W_DIM * C_DIM) + c0;
    for (int w = w0; w < 128; w += 8) {
        float sacc = zs[0][c].x + ((w & 1) ? -zs[64][c].x : zs[64][c].x);
        for (int k = 1; k < 64; ++k) {
            int t = (k * w) & 127;
            float2 z = zs[k][c];
            sacc = fmaf(2.f * z.x, cs[t], fmaf(-2.f * z.y, sn[t], sacc));
        }
        size_t oidx = obase + (size_t)w * C_DIM + c;
        out[oidx] = sacc + x[oidx];
    }
}

// ---------------------------------------------------------------------------
extern "C" void kernel_launch(void* const* d_in, const int* in_sizes, int n_in,
                              void* d_out, int out_size, void* d_ws, size_t ws_size,
                              hipStream_t stream) {
    const float* x  = (const float*)d_in[0];
    const float* w1 = (const float*)d_in[1];
    const float* b1 = (const float*)d_in[2];
    const float* w2 = (const float*)d_in[3];
    const float* b2 = (const float*)d_in[4];
    float* out = (float*)d_out;
    float2* S  = (float2*)d_ws;          // (B,H,WF,C) complex64 = 409 MB

    k1_rfft_w<<<dim3(B_DIM * H_DIM * 12), dim3(256), 0, stream>>>(x, S);
    k_fft_h<false><<<dim3(B_DIM * WF * 24), dim3(256), 0, stream>>>(S);
    k3_mlp<<<dim3((B_DIM * H_DIM * WF) / 16, NBLK), dim3(192), 0, stream>>>(S, w1, b1, w2, b2);
    k_fft_h<true><<<dim3(B_DIM * WF * 24), dim3(256), 0, stream>>>(S);
    k5_irfft_w<<<dim3(B_DIM * H_DIM * 24), dim3(256), 0, stream>>>(S, x, out);
}